// Round 10
// baseline (230.173 us; speedup 1.0000x reference)
//
#include <hip/hip_runtime.h>
#include <hip/hip_bf16.h>

// DIAGNOSTIC ROUND: exact R7 structure, whole body repeated x2 inside the
// kernel (writes identical values twice -- deterministic, validates). Purpose:
// lift dispatch duration above the harness's ~155us fill kernels so rocprof's
// top-5 finally shows OUR counters (WRITE_SIZE amplification question).
//
// X: [16, 2048, 128] f32, Y: [16, 2048, 128] f32 -> out: [16, 2048, 2048] f32
// out[b,n,m] = 1/(1+sqrt(max(||x||^2+||y||^2-2 x.y, 1e-7)))
#define Bb   16
#define Nn   2048
#define Mm   2048
#define Dd   128
#define TILE 128
#define NWG  (Bb * (Nn / TILE) * (Mm / TILE))   // 4096

typedef __attribute__((ext_vector_type(4))) float          f32x4;
typedef __attribute__((ext_vector_type(8))) unsigned short u16x8;
typedef __attribute__((ext_vector_type(8))) __bf16         bf16x8;

__device__ __forceinline__ unsigned short f32_to_bf16_rne(float f) {
  unsigned int u = __builtin_bit_cast(unsigned int, f);
  u += 0x7fffu + ((u >> 16) & 1u);
  return (unsigned short)(u >> 16);
}

__global__ __launch_bounds__(512, 4)
void dist_sim_kernel(const float* __restrict__ X, const float* __restrict__ Y,
                     float* __restrict__ out) {
  __shared__ alignas(16) unsigned short Xs[TILE * Dd];  // 32 KB bf16, swizzled
  __shared__ alignas(16) unsigned short Ys[TILE * Dd];  // 32 KB
  __shared__ alignas(16) float xsq[TILE];
  __shared__ alignas(16) float ysq[TILE];

  const int tid = threadIdx.x;

  // Bijective XCD-chunked swizzle (NWG % 8 == 0), bm fastest.
  const int wg  = blockIdx.x;
  const int swz = (wg & 7) * (NWG / 8) + (wg >> 3);
  const int bm  = swz & 15;
  const int bn  = (swz >> 4) & 15;
  const int b   = swz >> 8;

  const float* Xb = X + ((size_t)b * Nn + (size_t)bn * TILE) * Dd;
  const float* Yb = Y + ((size_t)b * Mm + (size_t)bm * TILE) * Dd;

  // Staging map: 4 threads per 128-float row; thread covers 32 floats.
  const int row = tid >> 2;          // 0..127
  const int c0  = (tid & 3) * 32;    // 0,32,64,96

  const int lane = tid & 63;
  const int wid  = tid >> 6;           // 0..7
  const int wr   = (wid >> 2) * 64;    // 0 or 64
  const int wc   = (wid & 3) * 32;     // 0,32,64,96
  const int fr   = lane & 15;
  const int kg   = lane >> 4;          // 0..3

  for (int rep = 0; rep < 2; ++rep) {
    __syncthreads();  // protect LDS re-stage from previous rep's readers

    // ---- stage BOTH tiles, full K, in one burst ----------------------------
    {
      const float* px = Xb + row * Dd + c0;
      const float* py = Yb + row * Dd + c0;
      f32x4 vx[8], vy[8];
      #pragma unroll
      for (int q = 0; q < 8; ++q) vx[q] = *(const f32x4*)(px + 4 * q);
      #pragma unroll
      for (int q = 0; q < 8; ++q) vy[q] = *(const f32x4*)(py + 4 * q);

      float sx = 0.f, sy = 0.f;
      #pragma unroll
      for (int q = 0; q < 4; ++q) {
        u16x8 wx, wy;
        #pragma unroll
        for (int e = 0; e < 4; ++e) {
          const float x0 = vx[2 * q][e], x1 = vx[2 * q + 1][e];
          const float y0 = vy[2 * q][e], y1 = vy[2 * q + 1][e];
          sx += x0 * x0 + x1 * x1;
          sy += y0 * y0 + y1 * y1;
          wx[e] = f32_to_bf16_rne(x0); wx[e + 4] = f32_to_bf16_rne(x1);
          wy[e] = f32_to_bf16_rne(y0); wy[e + 4] = f32_to_bf16_rne(y1);
        }
        const int idx = (row * Dd + c0 + q * 8) ^ ((row & 7) << 3);
        *(u16x8*)&Xs[idx] = wx;
        *(u16x8*)&Ys[idx] = wy;
      }
      sx += __shfl_xor(sx, 1); sy += __shfl_xor(sy, 1);
      sx += __shfl_xor(sx, 2); sy += __shfl_xor(sy, 2);
      if ((tid & 3) == 0) { xsq[row] = sx; ysq[row] = sy; }
    }

    f32x4 acc[4][2];
    #pragma unroll
    for (int i = 0; i < 4; ++i)
      #pragma unroll
      for (int j = 0; j < 2; ++j)
        acc[i][j] = (f32x4){0.f, 0.f, 0.f, 0.f};

    __syncthreads();

    // ---- MFMA: 4 k-steps, swapped operands: D[m-frag][n-frag] --------------
    #pragma unroll
    for (int kk = 0; kk < 4; ++kk) {
      const int k0 = kk * 32 + kg * 8;
      bf16x8 a[4], bb[2];
      #pragma unroll
      for (int i = 0; i < 4; ++i) {
        const int r_ = wr + i * 16 + fr;
        const int idx = (r_ * Dd + k0) ^ ((r_ & 7) << 3);
        a[i] = __builtin_bit_cast(bf16x8, *(const u16x8*)&Xs[idx]);
      }
      #pragma unroll
      for (int j = 0; j < 2; ++j) {
        const int r_ = wc + j * 16 + fr;
        const int idx = (r_ * Dd + k0) ^ ((r_ & 7) << 3);
        bb[j] = __builtin_bit_cast(bf16x8, *(const u16x8*)&Ys[idx]);
      }
      #pragma unroll
      for (int i = 0; i < 4; ++i)
        #pragma unroll
        for (int j = 0; j < 2; ++j)
          acc[i][j] = __builtin_amdgcn_mfma_f32_16x16x32_bf16(bb[j], a[i], acc[i][j], 0, 0, 0);
    }

    // ---- epilogue ----------------------------------------------------------
    float xv[4];
    #pragma unroll
    for (int i = 0; i < 4; ++i) xv[i] = xsq[wr + i * 16 + fr];
    f32x4 yv[2];
    #pragma unroll
    for (int j = 0; j < 2; ++j) yv[j] = *(const f32x4*)&ysq[wc + j * 16 + kg * 4];

    float* outb = out + (size_t)b * Nn * Mm
                + (size_t)(bn * TILE) * Mm + bm * TILE;
    #pragma unroll
    for (int i = 0; i < 4; ++i) {
      float* orow = outb + (size_t)(wr + i * 16 + fr) * Mm;
      #pragma unroll
      for (int j = 0; j < 2; ++j) {
        f32x4 ov;
        #pragma unroll
        for (int r = 0; r < 4; ++r) {
          float d2 = fmaf(-2.0f, acc[i][j][r], xv[i] + yv[j][r]);
          d2 = fmaxf(d2, 1e-7f);
          ov[r] = __builtin_amdgcn_rcpf(1.0f + __builtin_amdgcn_sqrtf(d2));
        }
        *(f32x4*)&orow[wc + j * 16 + kg * 4] = ov;
      }
    }
  }
}

extern "C" void kernel_launch(void* const* d_in, const int* in_sizes, int n_in,
                              void* d_out, int out_size, void* d_ws, size_t ws_size,
                              hipStream_t stream) {
  const float* X = (const float*)d_in[0];
  const float* Y = (const float*)d_in[1];
  float* out = (float*)d_out;
  dist_sim_kernel<<<dim3(NWG), dim3(512, 1, 1), 0, stream>>>(X, Y, out);
}

// Round 11
// 79.611 us; speedup vs baseline: 2.8912x; 2.8912x over previous
//
#include <hip/hip_runtime.h>
#include <hip/hip_bf16.h>

// X: [16, 2048, 128] f32, Y: [16, 2048, 128] f32 -> out: [16, 2048, 2048] f32
// out[b,n,m] = 1/(1+sqrt(max(||x||^2+||y||^2-2 x.y, 1e-7)))
//
// Two-phase: (1) prep kernel converts X,Y -> bf16 tiles PRE-SWIZZLED in d_ws
// + f32 row norms; (2) hot kernel = R7 structure (128^2 tile, 2 blocks/CU,
// swapped-operand MFMA) but staging is 8x global_load_lds(16B) of bf16 --
// 4x less issued input traffic, zero convert VALU, no staging VGPRs.
#define Bb   16
#define Nn   2048
#define Mm   2048
#define Dd   128
#define TILE 128
#define NWG  (Bb * (Nn / TILE) * (Mm / TILE))   // 4096
#define TILE_ELEMS (TILE * Dd)                   // 16384 shorts = 32 KB

typedef __attribute__((ext_vector_type(4))) float          f32x4;
typedef __attribute__((ext_vector_type(8))) unsigned short u16x8;
typedef __attribute__((ext_vector_type(8))) __bf16         bf16x8;

__device__ __forceinline__ unsigned short f32_to_bf16_rne(float f) {
  unsigned int u = __builtin_bit_cast(unsigned int, f);
  u += 0x7fffu + ((u >> 16) & 1u);
  return (unsigned short)(u >> 16);
}

// ---------------- prep: f32 -> swizzled bf16 tiles + f32 norms --------------
// 512 blocks: id<256 -> X tile (b=id>>4, t=id&15), else Y tile.
__global__ __launch_bounds__(512)
void prep_kernel(const float* __restrict__ X, const float* __restrict__ Y,
                 unsigned short* __restrict__ Xw, unsigned short* __restrict__ Yw,
                 float* __restrict__ Xn, float* __restrict__ Yn) {
  const int id  = blockIdx.x;
  const int isY = id >> 8;
  const int tb  = id & 255;
  const int b   = tb >> 4;
  const int t   = tb & 15;

  const float* src = (isY ? Y : X) + ((size_t)b * 2048 + (size_t)t * TILE) * Dd;
  unsigned short* dw = (isY ? Yw : Xw) + (size_t)tb * TILE_ELEMS;
  float* dn = (isY ? Yn : Xn) + b * 2048 + t * TILE;

  const int tid = threadIdx.x;
  const int row = tid >> 2;          // 0..127
  const int c0  = (tid & 3) * 32;    // 0,32,64,96

  const float* p = src + row * Dd + c0;
  f32x4 v[8];
  #pragma unroll
  for (int q = 0; q < 8; ++q) v[q] = *(const f32x4*)(p + 4 * q);

  float s = 0.f;
  #pragma unroll
  for (int q = 0; q < 4; ++q) {
    u16x8 w;
    #pragma unroll
    for (int e = 0; e < 4; ++e) {
      const float a0 = v[2 * q][e], a1 = v[2 * q + 1][e];
      s += a0 * a0 + a1 * a1;
      w[e] = f32_to_bf16_rne(a0); w[e + 4] = f32_to_bf16_rne(a1);
    }
    const int idx = (row * Dd + c0 + q * 8) ^ ((row & 7) << 3);  // pre-swizzle
    *(u16x8*)&dw[idx] = w;
  }
  s += __shfl_xor(s, 1);
  s += __shfl_xor(s, 2);
  if ((tid & 3) == 0) dn[row] = s;
}

// ---------------- hot: gload_lds staging + MFMA + fused epilogue ------------
__global__ __launch_bounds__(512, 4)
void dist_sim_kernel(const unsigned short* __restrict__ Xw,
                     const unsigned short* __restrict__ Yw,
                     const float* __restrict__ Xn, const float* __restrict__ Yn,
                     float* __restrict__ out) {
  __shared__ alignas(16) unsigned short Xs[TILE_ELEMS];  // 32 KB (swizzled)
  __shared__ alignas(16) unsigned short Ys[TILE_ELEMS];  // 32 KB
  // 64 KB + overhead -> 2 blocks/CU (the write-clean regime).

  const int tid = threadIdx.x;

  // Bijective XCD-chunked swizzle (NWG % 8 == 0), bm fastest.
  const int wg  = blockIdx.x;
  const int swz = (wg & 7) * (NWG / 8) + (wg >> 3);
  const int bm  = swz & 15;
  const int bn  = (swz >> 4) & 15;
  const int b   = swz >> 8;

  const unsigned short* xsrc = Xw + (size_t)(b * 16 + bn) * TILE_ELEMS;
  const unsigned short* ysrc = Yw + (size_t)(b * 16 + bm) * TILE_ELEMS;

  // Linear async copy: pre-swizzled source -> linear LDS dest (rule #21).
  // Per round: 512 thr x 16B = 8 KB; lane offset = lane*16B matches HW layout.
  #pragma unroll
  for (int it = 0; it < 4; ++it) {
    const int off = it * 4096 + tid * 8;  // shorts
    __builtin_amdgcn_global_load_lds(
        (const __attribute__((address_space(1))) void*)(xsrc + off),
        (__attribute__((address_space(3))) void*)(Xs + off), 16, 0, 0);
  }
  #pragma unroll
  for (int it = 0; it < 4; ++it) {
    const int off = it * 4096 + tid * 8;
    __builtin_amdgcn_global_load_lds(
        (const __attribute__((address_space(1))) void*)(ysrc + off),
        (__attribute__((address_space(3))) void*)(Ys + off), 16, 0, 0);
  }

  const int lane = tid & 63;
  const int wid  = tid >> 6;           // 0..7
  const int wr   = (wid >> 2) * 64;    // 0 or 64
  const int wc   = (wid & 3) * 32;     // 0,32,64,96
  const int fr   = lane & 15;
  const int kg   = lane >> 4;          // 0..3

  f32x4 acc[4][2];
  #pragma unroll
  for (int i = 0; i < 4; ++i)
    #pragma unroll
    for (int j = 0; j < 2; ++j)
      acc[i][j] = (f32x4){0.f, 0.f, 0.f, 0.f};

  __syncthreads();  // waits vmcnt(0): gload_lds complete

  // ---- MFMA: 4 k-steps, swapped operands: D[m-frag][n-frag] ----------------
  // acc[i][j] (lane fr,kg; reg r): n = wr+i*16+fr, m = wc+j*16+kg*4+r
  #pragma unroll
  for (int kk = 0; kk < 4; ++kk) {
    const int k0 = kk * 32 + kg * 8;
    bf16x8 a[4], bb[2];
    #pragma unroll
    for (int i = 0; i < 4; ++i) {
      const int r_ = wr + i * 16 + fr;
      const int idx = (r_ * Dd + k0) ^ ((r_ & 7) << 3);
      a[i] = __builtin_bit_cast(bf16x8, *(const u16x8*)&Xs[idx]);
    }
    #pragma unroll
    for (int j = 0; j < 2; ++j) {
      const int r_ = wc + j * 16 + fr;
      const int idx = (r_ * Dd + k0) ^ ((r_ & 7) << 3);
      bb[j] = __builtin_bit_cast(bf16x8, *(const u16x8*)&Ys[idx]);
    }
    #pragma unroll
    for (int i = 0; i < 4; ++i)
      #pragma unroll
      for (int j = 0; j < 2; ++j)
        acc[i][j] = __builtin_amdgcn_mfma_f32_16x16x32_bf16(bb[j], a[i], acc[i][j], 0, 0, 0);
  }

  // ---- epilogue: norms from global (L2-hot), d2 -> 1/(1+sqrt(d2)) ----------
  const float* Xnb = Xn + b * 2048 + bn * TILE;
  const float* Ynb = Yn + b * 2048 + bm * TILE;
  float xv[4];
  #pragma unroll
  for (int i = 0; i < 4; ++i) xv[i] = Xnb[wr + i * 16 + fr];
  f32x4 yv[2];
  #pragma unroll
  for (int j = 0; j < 2; ++j) yv[j] = *(const f32x4*)&Ynb[wc + j * 16 + kg * 4];

  float* outb = out + (size_t)b * Nn * Mm
              + (size_t)(bn * TILE) * Mm + bm * TILE;
  #pragma unroll
  for (int i = 0; i < 4; ++i) {
    float* orow = outb + (size_t)(wr + i * 16 + fr) * Mm;
    #pragma unroll
    for (int j = 0; j < 2; ++j) {
      f32x4 ov;
      #pragma unroll
      for (int r = 0; r < 4; ++r) {
        float d2 = fmaf(-2.0f, acc[i][j][r], xv[i] + yv[j][r]);
        d2 = fmaxf(d2, 1e-7f);
        ov[r] = __builtin_amdgcn_rcpf(1.0f + __builtin_amdgcn_sqrtf(d2));
      }
      *(f32x4*)&orow[wc + j * 16 + kg * 4] = ov;
    }
  }
}

// ---------------- fallback: proven R7 single-kernel (ws too small) ----------
__global__ __launch_bounds__(512, 4)
void dist_sim_fallback(const float* __restrict__ X, const float* __restrict__ Y,
                       float* __restrict__ out) {
  __shared__ alignas(16) unsigned short Xs[TILE_ELEMS];
  __shared__ alignas(16) unsigned short Ys[TILE_ELEMS];
  __shared__ alignas(16) float xsq[TILE];
  __shared__ alignas(16) float ysq[TILE];

  const int tid = threadIdx.x;
  const int wg  = blockIdx.x;
  const int swz = (wg & 7) * (NWG / 8) + (wg >> 3);
  const int bm  = swz & 15;
  const int bn  = (swz >> 4) & 15;
  const int b   = swz >> 8;

  const float* Xb = X + ((size_t)b * Nn + (size_t)bn * TILE) * Dd;
  const float* Yb = Y + ((size_t)b * Mm + (size_t)bm * TILE) * Dd;
  const int row = tid >> 2;
  const int c0  = (tid & 3) * 32;
  {
    const float* px = Xb + row * Dd + c0;
    const float* py = Yb + row * Dd + c0;
    f32x4 vx[8], vy[8];
    #pragma unroll
    for (int q = 0; q < 8; ++q) vx[q] = *(const f32x4*)(px + 4 * q);
    #pragma unroll
    for (int q = 0; q < 8; ++q) vy[q] = *(const f32x4*)(py + 4 * q);
    float sx = 0.f, sy = 0.f;
    #pragma unroll
    for (int q = 0; q < 4; ++q) {
      u16x8 wx, wy;
      #pragma unroll
      for (int e = 0; e < 4; ++e) {
        const float x0 = vx[2 * q][e], x1 = vx[2 * q + 1][e];
        const float y0 = vy[2 * q][e], y1 = vy[2 * q + 1][e];
        sx += x0 * x0 + x1 * x1; sy += y0 * y0 + y1 * y1;
        wx[e] = f32_to_bf16_rne(x0); wx[e + 4] = f32_to_bf16_rne(x1);
        wy[e] = f32_to_bf16_rne(y0); wy[e + 4] = f32_to_bf16_rne(y1);
      }
      const int idx = (row * Dd + c0 + q * 8) ^ ((row & 7) << 3);
      *(u16x8*)&Xs[idx] = wx; *(u16x8*)&Ys[idx] = wy;
    }
    sx += __shfl_xor(sx, 1); sy += __shfl_xor(sy, 1);
    sx += __shfl_xor(sx, 2); sy += __shfl_xor(sy, 2);
    if ((tid & 3) == 0) { xsq[row] = sx; ysq[row] = sy; }
  }
  const int lane = tid & 63, wid = tid >> 6;
  const int wr = (wid >> 2) * 64, wc = (wid & 3) * 32;
  const int fr = lane & 15, kg = lane >> 4;
  f32x4 acc[4][2];
  #pragma unroll
  for (int i = 0; i < 4; ++i)
    #pragma unroll
    for (int j = 0; j < 2; ++j) acc[i][j] = (f32x4){0.f, 0.f, 0.f, 0.f};
  __syncthreads();
  #pragma unroll
  for (int kk = 0; kk < 4; ++kk) {
    const int k0 = kk * 32 + kg * 8;
    bf16x8 a[4], bb[2];
    #pragma unroll
    for (int i = 0; i < 4; ++i) {
      const int r_ = wr + i * 16 + fr;
      a[i] = __builtin_bit_cast(bf16x8, *(const u16x8*)&Xs[(r_ * Dd + k0) ^ ((r_ & 7) << 3)]);
    }
    #pragma unroll
    for (int j = 0; j < 2; ++j) {
      const int r_ = wc + j * 16 + fr;
      bb[j] = __builtin_bit_cast(bf16x8, *(const u16x8*)&Ys[(r_ * Dd + k0) ^ ((r_ & 7) << 3)]);
    }
    #pragma unroll
    for (int i = 0; i < 4; ++i)
      #pragma unroll
      for (int j = 0; j < 2; ++j)
        acc[i][j] = __builtin_amdgcn_mfma_f32_16x16x32_bf16(bb[j], a[i], acc[i][j], 0, 0, 0);
  }
  float xv[4];
  #pragma unroll
  for (int i = 0; i < 4; ++i) xv[i] = xsq[wr + i * 16 + fr];
  f32x4 yv[2];
  #pragma unroll
  for (int j = 0; j < 2; ++j) yv[j] = *(const f32x4*)&ysq[wc + j * 16 + kg * 4];
  float* outb = out + (size_t)b * Nn * Mm + (size_t)(bn * TILE) * Mm + bm * TILE;
  #pragma unroll
  for (int i = 0; i < 4; ++i) {
    float* orow = outb + (size_t)(wr + i * 16 + fr) * Mm;
    #pragma unroll
    for (int j = 0; j < 2; ++j) {
      f32x4 ov;
      #pragma unroll
      for (int r = 0; r < 4; ++r) {
        float d2 = fmaf(-2.0f, acc[i][j][r], xv[i] + yv[j][r]);
        d2 = fmaxf(d2, 1e-7f);
        ov[r] = __builtin_amdgcn_rcpf(1.0f + __builtin_amdgcn_sqrtf(d2));
      }
      *(f32x4*)&orow[wc + j * 16 + kg * 4] = ov;
    }
  }
}

extern "C" void kernel_launch(void* const* d_in, const int* in_sizes, int n_in,
                              void* d_out, int out_size, void* d_ws, size_t ws_size,
                              hipStream_t stream) {
  const float* X = (const float*)d_in[0];
  const float* Y = (const float*)d_in[1];
  float* out = (float*)d_out;

  const size_t XwB = (size_t)256 * TILE_ELEMS * 2;   // 8 MB
  const size_t NnB = (size_t)16 * 2048 * 4;          // 128 KB
  const size_t need = 2 * XwB + 2 * NnB;             // ~16.25 MB

  if (ws_size < need) {  // safety net: proven R7 path
    dist_sim_fallback<<<dim3(NWG), dim3(512, 1, 1), 0, stream>>>(X, Y, out);
    return;
  }

  char* ws = (char*)d_ws;
  unsigned short* Xw = (unsigned short*)ws;
  unsigned short* Yw = (unsigned short*)(ws + XwB);
  float* Xn = (float*)(ws + 2 * XwB);
  float* Yn = (float*)(ws + 2 * XwB + NnB);

  prep_kernel<<<dim3(512), dim3(512, 1, 1), 0, stream>>>(X, Y, Xw, Yw, Xn, Yn);
  dist_sim_kernel<<<dim3(NWG), dim3(512, 1, 1), 0, stream>>>(Xw, Yw, Xn, Yn, out);
}